// Round 14
// baseline (53.049 us; speedup 1.0000x reference)
//
#include <hip/hip_runtime.h>
#include <math.h>

typedef __attribute__((ext_vector_type(8))) short bf16x8;
typedef __attribute__((ext_vector_type(4))) float f32x4;
typedef __attribute__((ext_vector_type(4))) unsigned int u32x4;

#define B_ 4
#define L_ 2048
#define S_ 2048
#define H_ 8
#define E_ 64
#define D_ 64
#define NT_ 32
#define TILE_BYTES 16384
#define WS_NEEDED ((size_t)B_ * H_ * NT_ * TILE_BYTES)   // 16 MB tile images
#define SCL (0.125f * 1.44269504088896f)                  // 1/sqrt(E) * log2(e)

__device__ __forceinline__ unsigned short f2bf(float x) {
    unsigned int u = __builtin_bit_cast(unsigned int, x);
    u += 0x7fffu + ((u >> 16) & 1u);
    return (unsigned short)(u >> 16);
}
// kv-row permute so S^T C-fragment layout == PV A-operand layout (verified rounds 1-13)
__device__ __forceinline__ int rho(int r) {
    return (r & 32) | (((r >> 2) & 1) << 4) | (((r >> 3) & 3) << 2) | (r & 3);
}
__device__ __forceinline__ void gload16(const void* g, void* l) {
    __builtin_amdgcn_global_load_lds((const __attribute__((address_space(1))) unsigned int*)g,
                                     (__attribute__((address_space(3))) unsigned int*)l, 16, 0, 0);
}

// ---------------- prep: K -> bf16 tile image, V -> V^T image; XCD-aligned to consumer ----------------
__global__ __launch_bounds__(256) void prep_kv(const float* __restrict__ K,
                                               const float* __restrict__ V,
                                               unsigned short* __restrict__ ws)
{
    __shared__ __align__(16) unsigned short vt[64][80];
    const int tid = threadIdx.x;
    const int bid = blockIdx.x;
    const int kt  = bid >> 5;
    const int bh  = (((bid >> 3) & 3) << 3) | (bid & 7);      // bid%8 == bh%8
    const int b   = bh >> 3, h = bh & 7;
    const int s0  = kt * 64;
    const int r   = tid >> 2;
    const int e0  = (tid & 3) * 16;

    const float* krow = K + (((size_t)(b * S_ + s0 + r)) * H_ + h) * E_ + e0;
    const float* vrow = V + (((size_t)(b * S_ + s0 + r)) * H_ + h) * D_ + e0;
    char* tile = (char*)(ws) + ((size_t)(bh * NT_ + kt) * TILE_BYTES);

    unsigned short kb[16];
    #pragma unroll
    for (int i = 0; i < 4; ++i) {
        f32x4 k4 = *(const f32x4*)(krow + i * 4);
        #pragma unroll
        for (int jq = 0; jq < 4; ++jq) kb[i * 4 + jq] = f2bf(k4[jq]);
    }
    {
        const int rr = rho(r);
        const int m  = (rr & 7) << 4;
        char* kbase = tile + rr * 128;
        u32x4 lo, hi;
        #pragma unroll
        for (int jq = 0; jq < 4; ++jq) {
            lo[jq] = (unsigned)kb[2 * jq] | ((unsigned)kb[2 * jq + 1] << 16);
            hi[jq] = (unsigned)kb[8 + 2 * jq] | ((unsigned)kb[9 + 2 * jq] << 16);
        }
        *(u32x4*)(kbase + ((2 * e0) ^ m))      = lo;
        *(u32x4*)(kbase + ((2 * e0 + 16) ^ m)) = hi;
    }
    #pragma unroll
    for (int i = 0; i < 4; ++i) {
        f32x4 v4 = *(const f32x4*)(vrow + i * 4);
        #pragma unroll
        for (int jq = 0; jq < 4; ++jq) vt[e0 + i * 4 + jq][r] = f2bf(v4[jq]);
    }
    __syncthreads();
    {
        const int d  = tid >> 2;
        const int c0 = (tid & 3) * 16;
        const int m  = (d & 7) << 4;
        char* vbase = tile + 8192 + d * 128;
        u32x4 lo = *(const u32x4*)&vt[d][c0];
        u32x4 hi = *(const u32x4*)&vt[d][c0 + 8];
        *(u32x4*)(vbase + ((2 * c0) ^ m))      = lo;
        *(u32x4*)(vbase + ((2 * c0 + 16) ^ m)) = hi;
    }
}

// ---- attn14: 8 waves = 4 kv-teams x 2 row-waves(64 q-rows), paired groups {gg,15-gg} = 9 iters ----
// pool during loop: team t -> [t*32768 .. t*32768+2*16384); during combine: sacc[3*128][68] + sls[3*128]
__device__ __forceinline__ void do_grp14(
    const float* __restrict__ Q, const char* __restrict__ tb, char* __restrict__ pool,
    int b0, int h, int gg, int team, int lw, int lq, int gl, int tid,
    float* __restrict__ O)
{
    const int nt = 2 * gg + 2;
    const int kb = (nt * team) >> 2;
    const int ke = (nt * (team + 1)) >> 2;
    const int M  = (nt + 3) >> 2;                 // same for all teams -> lockstep barriers
    const int c  = 2 * gg + lw;                   // this wave's 64-row chunk (diag tile == c)

    int qrow[4];
    #pragma unroll
    for (int qs = 0; qs < 4; ++qs) qrow[qs] = c * 64 + qs * 16 + lq;

    // Q fragments (B-operand), scale*log2e folded => scores in exp2 domain
    bf16x8 qf[4][2];
    #pragma unroll
    for (int qs = 0; qs < 4; ++qs) {
        const float* qptr = Q + (((size_t)(b0 * L_ + qrow[qs])) * H_ + h) * E_;
        #pragma unroll
        for (int eb = 0; eb < 2; ++eb) {
            const float* pq = qptr + eb * 32 + gl * 8;
            f32x4 a = *(const f32x4*)pq;
            f32x4 b = *(const f32x4*)(pq + 4);
            bf16x8 qv;
            #pragma unroll
            for (int k = 0; k < 4; ++k) {
                qv[k]     = (short)f2bf(a[k] * SCL);
                qv[4 + k] = (short)f2bf(b[k] * SCL);
            }
            qf[qs][eb] = qv;
        }
    }

    f32x4 acc[4][4] = {};
    float ls[4] = {0.f, 0.f, 0.f, 0.f};

    const int soff = tid & 127;                   // 128 staging threads per team
    char* myb = pool + team * 32768;

    #define STAGE14(I, BUF) do { \
        int ti = kb + (I); if (ti > nt - 1) ti = nt - 1; \
        const char* gp = tb + (size_t)ti * TILE_BYTES + soff * 16; \
        char* lp = myb + (BUF) * 16384 + soff * 16; \
        _Pragma("unroll") \
        for (int r8 = 0; r8 < 8; ++r8) \
            gload16(gp + r8 * 2048, lp + r8 * 2048); \
    } while (0)

    STAGE14(0, 0);
    int buf = 0;
    for (int i = 0; i < M; ++i) {
        if (i + 1 < M) {
            STAGE14(i + 1, buf ^ 1);
            asm volatile("s_waitcnt vmcnt(8)" ::: "memory");
        } else {
            asm volatile("s_waitcnt vmcnt(0)" ::: "memory");
        }
        __builtin_amdgcn_s_barrier();
        __builtin_amdgcn_sched_barrier(0);

        const int kt = kb + i;
        if (kt < ke && kt <= c) {
            const char* Kl = myb + buf * 16384;
            const char* Vl = Kl + 8192;
            const int kv0 = kt * 64;
            const bool maskit = (kt == c);

            u32x4 pw[4][2];
            #pragma unroll
            for (int st = 0; st < 4; ++st) {
                const int row = st * 16 + lq;
                const int mm = (row & 7) << 4;
                const char* kr = Kl + row * 128;
                bf16x8 k0 = *(const bf16x8*)(kr + ((16 * gl) ^ mm));
                bf16x8 k1 = *(const bf16x8*)(kr + ((64 + 16 * gl) ^ mm));
                #pragma unroll
                for (int qs = 0; qs < 4; ++qs) {
                    f32x4 z = {0.f, 0.f, 0.f, 0.f};
                    __builtin_amdgcn_s_setprio(1);
                    f32x4 cc = __builtin_amdgcn_mfma_f32_16x16x32_bf16(k0, qf[qs][0], z, 0, 0, 0);
                    cc = __builtin_amdgcn_mfma_f32_16x16x32_bf16(k1, qf[qs][1], cc, 0, 0, 0);
                    __builtin_amdgcn_s_setprio(0);
                    if (maskit) {
                        #pragma unroll
                        for (int r = 0; r < 4; ++r) {
                            const int kv = kv0 + 32 * (st >> 1) + 8 * gl + 4 * (st & 1) + r;
                            if (kv > qrow[qs]) cc[r] = -INFINITY;
                        }
                    }
                    f32x4 ev;
                    #pragma unroll
                    for (int r = 0; r < 4; ++r)
                        asm("v_exp_f32 %0, %1" : "=v"(ev[r]) : "v"(cc[r]));
                    ls[qs] += (ev[0] + ev[1]) + (ev[2] + ev[3]);
                    asm("v_cvt_pk_bf16_f32 %0, %1, %2" : "=v"(pw[qs][st >> 1][2 * (st & 1)])     : "v"(ev[0]), "v"(ev[1]));
                    asm("v_cvt_pk_bf16_f32 %0, %1, %2" : "=v"(pw[qs][st >> 1][2 * (st & 1) + 1]) : "v"(ev[2]), "v"(ev[3]));
                }
            }

            #pragma unroll
            for (int dt = 0; dt < 4; ++dt) {
                const int row = dt * 16 + lq;
                const int mm = (row & 7) << 4;
                bf16x8 v0 = *(const bf16x8*)(Vl + row * 128 + ((16 * gl) ^ mm));
                bf16x8 v1 = *(const bf16x8*)(Vl + row * 128 + ((64 + 16 * gl) ^ mm));
                __builtin_amdgcn_s_setprio(1);
                #pragma unroll
                for (int qs = 0; qs < 4; ++qs) {
                    acc[qs][dt] = __builtin_amdgcn_mfma_f32_16x16x32_bf16(v0, __builtin_bit_cast(bf16x8, pw[qs][0]), acc[qs][dt], 0, 0, 0);
                    acc[qs][dt] = __builtin_amdgcn_mfma_f32_16x16x32_bf16(v1, __builtin_bit_cast(bf16x8, pw[qs][1]), acc[qs][dt], 0, 0, 0);
                }
                __builtin_amdgcn_s_setprio(0);
            }
        }
        __builtin_amdgcn_s_barrier();
        buf ^= 1;
    }
    #undef STAGE14

    // ---- in-block 4-way combine (pool aliased; tile bufs dead after final barrier) ----
    float (*sacc)[68] = (float(*)[68])pool;            // [3*128][68]
    float* sls = (float*)(pool + 3 * 128 * 68 * 4);    // [3*128]
    if (team != 0) {
        #pragma unroll
        for (int qs = 0; qs < 4; ++qs) {
            float l = ls[qs] + __shfl_xor(ls[qs], 16);
            l += __shfl_xor(l, 32);
            const int rowl = (team - 1) * 128 + lw * 64 + qs * 16 + lq;
            if (gl == 0) sls[rowl] = l;
            #pragma unroll
            for (int dt = 0; dt < 4; ++dt)
                *(f32x4*)&sacc[rowl][dt * 16 + 4 * gl] = acc[qs][dt];
        }
    }
    __syncthreads();
    if (team == 0) {
        #pragma unroll
        for (int qs = 0; qs < 4; ++qs) {
            float l = ls[qs] + __shfl_xor(ls[qs], 16);
            l += __shfl_xor(l, 32);
            const int rl = lw * 64 + qs * 16 + lq;
            l += sls[rl] + sls[128 + rl] + sls[256 + rl];
            const float inv = 1.0f / l;
            float* op = O + (((size_t)(b0 * L_ + qrow[qs])) * H_ + h) * D_;
            #pragma unroll
            for (int dt = 0; dt < 4; ++dt) {
                const int dc = dt * 16 + 4 * gl;
                f32x4 p0 = *(const f32x4*)&sacc[rl][dc];
                f32x4 p1 = *(const f32x4*)&sacc[128 + rl][dc];
                f32x4 p2 = *(const f32x4*)&sacc[256 + rl][dc];
                f32x4 o;
                #pragma unroll
                for (int r = 0; r < 4; ++r)
                    o[r] = (acc[qs][dt][r] + p0[r] + p1[r] + p2[r]) * inv;
                *(f32x4*)(op + dc) = o;
            }
        }
    }
    __syncthreads();   // combine reads done before pool is restaged by next group
}

__global__ __launch_bounds__(512, 2) void attn14(const float* __restrict__ Q,
                                                 const unsigned short* __restrict__ ws,
                                                 float* __restrict__ O)
{
    __shared__ __align__(16) char pool[131072];   // 4 teams x 2 bufs x 16KB

    const int tid  = threadIdx.x;
    const int lane = tid & 63;
    const int w    = tid >> 6;        // wave 0..7
    const int team = w >> 1;          // kv-split team 0..3
    const int lw   = w & 1;           // row-wave within team (64 rows each)
    const int lq   = lane & 15;
    const int gl   = lane >> 4;

    const int bid = blockIdx.x;
    const int bh  = bid & 31;         // XCD bh%8 == prep's XCD
    const int pj  = bid >> 5;         // 0..7
    const int b0  = bh >> 3, h = bh & 7;

    const char* tb = (const char*)ws + (size_t)bh * NT_ * TILE_BYTES;

    // complementary 128-row groups: ceil((2pj+2)/4) + ceil((2(15-pj)+2)/4) == 9 iters, all blocks equal
    do_grp14(Q, tb, pool, b0, h, pj,      team, lw, lq, gl, tid, O);
    do_grp14(Q, tb, pool, b0, h, 15 - pj, team, lw, lq, gl, tid, O);
}

// ---------------- fallback (round-1 kernel, proven) for tiny ws ----------------
#define KPITCH 72
__global__ __launch_bounds__(256, 2) void attn_fwd_fb(
    const float* __restrict__ Q, const float* __restrict__ K,
    const float* __restrict__ V, float* __restrict__ O)
{
    __shared__ unsigned short Klds[64 * KPITCH];
    __shared__ unsigned short Vlds[64 * KPITCH];
    const int tid = threadIdx.x, lane = tid & 63, w = tid >> 6;
    const int lq = lane & 15, g = lane >> 4;
    const int bid = blockIdx.x, qb = bid & 31, bh = bid >> 5;
    const int b0 = bh >> 3, h = bh & 7;
    const int q0 = qb * 64, qrow = q0 + w * 16 + lq;
    const float* qptr = Q + ((size_t)(b0 * L_ + qrow) * H_ + h) * E_;
    bf16x8 qf[2];
    #pragma unroll
    for (int eb = 0; eb < 2; ++eb) {
        const float* pp = qptr + eb * 32 + g * 8;
        f32x4 a = *(const f32x4*)pp; f32x4 b = *(const f32x4*)(pp + 4);
        bf16x8 qv;
        #pragma unroll
        for (int jq = 0; jq < 4; ++jq) { qv[jq] = (short)f2bf(a[jq] * 0.125f); qv[4 + jq] = (short)f2bf(b[jq] * 0.125f); }
        qf[eb] = qv;
    }
    const int tr = tid >> 2, tc = tid & 3;
    const int rh = rho(tr);
    f32x4 acc[4] = {};
    float mrow = -INFINITY, lrow = 0.f;
    for (int kt = 0; kt < qb + 1; ++kt) {
        const int kv0 = kt * 64;
        __syncthreads();
        {
            const float* krow = K + ((size_t)((b0 * S_ + kv0 + tr)) * H_ + h) * E_;
            const float* vrow = V + ((size_t)((b0 * S_ + kv0 + tr)) * H_ + h) * D_;
            #pragma unroll
            for (int i = 0; i < 4; ++i) {
                const int e0 = tc * 4 + i * 16;
                f32x4 k4 = *(const f32x4*)(krow + e0);
                unsigned int lo = (unsigned)f2bf(k4[0]) | ((unsigned)f2bf(k4[1]) << 16);
                unsigned int hi = (unsigned)f2bf(k4[2]) | ((unsigned)f2bf(k4[3]) << 16);
                *(uint2*)&Klds[rh * KPITCH + e0] = make_uint2(lo, hi);
                f32x4 v4 = *(const f32x4*)(vrow + e0);
                #pragma unroll
                for (int k2 = 0; k2 < 4; ++k2) Vlds[(e0 + k2) * KPITCH + tr] = f2bf(v4[k2]);
            }
        }
        __syncthreads();
        f32x4 sc[4];
        #pragma unroll
        for (int st = 0; st < 4; ++st) {
            const unsigned short* kr = &Klds[(st * 16 + lq) * KPITCH];
            bf16x8 ka0 = *(const bf16x8*)(kr + 8 * g);
            bf16x8 ka1 = *(const bf16x8*)(kr + 32 + 8 * g);
            f32x4 cc = {0.f, 0.f, 0.f, 0.f};
            cc = __builtin_amdgcn_mfma_f32_16x16x32_bf16(ka0, qf[0], cc, 0, 0, 0);
            cc = __builtin_amdgcn_mfma_f32_16x16x32_bf16(ka1, qf[1], cc, 0, 0, 0);
            sc[st] = cc;
        }
        float tmax = -INFINITY;
        #pragma unroll
        for (int st = 0; st < 4; ++st) {
            const int kvb = kv0 + 32 * (st >> 1) + 8 * g + 4 * (st & 1);
            #pragma unroll
            for (int r = 0; r < 4; ++r) { if (kvb + r > qrow) sc[st][r] = -INFINITY; tmax = fmaxf(tmax, sc[st][r]); }
        }
        tmax = fmaxf(tmax, __shfl_xor(tmax, 16));
        tmax = fmaxf(tmax, __shfl_xor(tmax, 32));
        const float mnew = fmaxf(mrow, tmax);
        const float corr = __expf(mrow - mnew);
        float pv[4][4]; float tsum = 0.f;
        #pragma unroll
        for (int st = 0; st < 4; ++st)
            #pragma unroll
            for (int r = 0; r < 4; ++r) { float e = __expf(sc[st][r] - mnew); pv[st][r] = e; tsum += e; }
        tsum += __shfl_xor(tsum, 16); tsum += __shfl_xor(tsum, 32);
        lrow = lrow * corr + tsum; mrow = mnew;
        #pragma unroll
        for (int dt = 0; dt < 4; ++dt)
            #pragma unroll
            for (int r = 0; r < 4; ++r) acc[dt][r] *= corr;
        bf16x8 pb[2];
        #pragma unroll
        for (int bb = 0; bb < 2; ++bb)
            #pragma unroll
            for (int s = 0; s < 2; ++s)
                #pragma unroll
                for (int r = 0; r < 4; ++r) pb[bb][4 * s + r] = (short)f2bf(pv[2 * bb + s][r]);
        #pragma unroll
        for (int bb = 0; bb < 2; ++bb)
            #pragma unroll
            for (int dt = 0; dt < 4; ++dt) {
                bf16x8 va = *(const bf16x8*)&Vlds[(dt * 16 + lq) * KPITCH + 32 * bb + 8 * g];
                acc[dt] = __builtin_amdgcn_mfma_f32_16x16x32_bf16(va, pb[bb], acc[dt], 0, 0, 0);
            }
    }
    const float inv = 1.0f / lrow;
    float* optr = O + ((size_t)(b0 * L_ + qrow) * H_ + h) * D_;
    #pragma unroll
    for (int dt = 0; dt < 4; ++dt) {
        f32x4 o;
        #pragma unroll
        for (int r = 0; r < 4; ++r) o[r] = acc[dt][r] * inv;
        *(f32x4*)(optr + dt * 16 + 4 * g) = o;
    }
}

extern "C" void kernel_launch(void* const* d_in, const int* in_sizes, int n_in,
                              void* d_out, int out_size, void* d_ws, size_t ws_size,
                              hipStream_t stream) {
    const float* Q = (const float*)d_in[0];
    const float* K = (const float*)d_in[1];
    const float* V = (const float*)d_in[2];
    float* O = (float*)d_out;
    if (ws_size >= WS_NEEDED) {
        prep_kv<<<dim3(B_ * H_ * NT_), 256, 0, stream>>>(K, V, (unsigned short*)d_ws);
        attn14<<<dim3(256), 512, 0, stream>>>(Q, (const unsigned short*)d_ws, O);
    } else {
        attn_fwd_fb<<<dim3(B_ * H_ * 32), 256, 0, stream>>>(Q, K, V, O);
    }
}

// Round 15
// 52.398 us; speedup vs baseline: 1.0124x; 1.0124x over previous
//
#include <hip/hip_runtime.h>
#include <math.h>

typedef __attribute__((ext_vector_type(8))) short bf16x8;
typedef __attribute__((ext_vector_type(4))) float f32x4;
typedef __attribute__((ext_vector_type(4))) unsigned int u32x4;

#define B_ 4
#define L_ 2048
#define S_ 2048
#define H_ 8
#define E_ 64
#define D_ 64
#define NT_ 32
#define TILE_BYTES 16384
#define WS_NEEDED ((size_t)B_ * H_ * NT_ * TILE_BYTES)   // 16 MB tile images
#define SCL (0.125f * 1.44269504088896f)                  // 1/sqrt(E) * log2(e)

__device__ __forceinline__ unsigned short f2bf(float x) {
    unsigned int u = __builtin_bit_cast(unsigned int, x);
    u += 0x7fffu + ((u >> 16) & 1u);
    return (unsigned short)(u >> 16);
}
// kv-row permute so S^T C-fragment layout == PV A-operand layout (verified rounds 1-14)
__device__ __forceinline__ int rho(int r) {
    return (r & 32) | (((r >> 2) & 1) << 4) | (((r >> 3) & 3) << 2) | (r & 3);
}

// ---------------- prep: K -> bf16 tile image, V -> V^T image; XCD-aligned to consumer ----------------
__global__ __launch_bounds__(256) void prep_kv(const float* __restrict__ K,
                                               const float* __restrict__ V,
                                               unsigned short* __restrict__ ws)
{
    __shared__ __align__(16) unsigned short vt[64][80];
    const int tid = threadIdx.x;
    const int bid = blockIdx.x;
    const int kt  = bid >> 5;
    const int bh  = (((bid >> 3) & 3) << 3) | (bid & 7);      // bid%8 == bh%8
    const int b   = bh >> 3, h = bh & 7;
    const int s0  = kt * 64;
    const int r   = tid >> 2;
    const int e0  = (tid & 3) * 16;

    const float* krow = K + (((size_t)(b * S_ + s0 + r)) * H_ + h) * E_ + e0;
    const float* vrow = V + (((size_t)(b * S_ + s0 + r)) * H_ + h) * D_ + e0;
    char* tile = (char*)(ws) + ((size_t)(bh * NT_ + kt) * TILE_BYTES);

    unsigned short kb[16];
    #pragma unroll
    for (int i = 0; i < 4; ++i) {
        f32x4 k4 = *(const f32x4*)(krow + i * 4);
        #pragma unroll
        for (int jq = 0; jq < 4; ++jq) kb[i * 4 + jq] = f2bf(k4[jq]);
    }
    {
        const int rr = rho(r);
        const int m  = (rr & 7) << 4;
        char* kbase = tile + rr * 128;
        u32x4 lo, hi;
        #pragma unroll
        for (int jq = 0; jq < 4; ++jq) {
            lo[jq] = (unsigned)kb[2 * jq] | ((unsigned)kb[2 * jq + 1] << 16);
            hi[jq] = (unsigned)kb[8 + 2 * jq] | ((unsigned)kb[9 + 2 * jq] << 16);
        }
        *(u32x4*)(kbase + ((2 * e0) ^ m))      = lo;
        *(u32x4*)(kbase + ((2 * e0 + 16) ^ m)) = hi;
    }
    #pragma unroll
    for (int i = 0; i < 4; ++i) {
        f32x4 v4 = *(const f32x4*)(vrow + i * 4);
        #pragma unroll
        for (int jq = 0; jq < 4; ++jq) vt[e0 + i * 4 + jq][r] = f2bf(v4[jq]);
    }
    __syncthreads();
    {
        const int d  = tid >> 2;
        const int c0 = (tid & 3) * 16;
        const int m  = (d & 7) << 4;
        char* vbase = tile + 8192 + d * 128;
        u32x4 lo = *(const u32x4*)&vt[d][c0];
        u32x4 hi = *(const u32x4*)&vt[d][c0 + 8];
        *(u32x4*)(vbase + ((2 * c0) ^ m))      = lo;
        *(u32x4*)(vbase + ((2 * c0 + 16) ^ m)) = hi;
    }
}

// ---- attn16: barrier-free register streaming, DEPTH-2 prefetch, uniform pairs {p,63-p} ----
#define GL16(dst, p, o) asm volatile("global_load_dwordx4 %0, %1, off offset:" o \
                                     : "=&v"(dst) : "v"(p) : "memory")

#define ISSUE8(ARR, BA, BB) do { \
    GL16(ARR[0], BA, "-3072"); GL16(ARR[1], BB, "-3072"); \
    GL16(ARR[2], BA, "-1024"); GL16(ARR[3], BB, "-1024"); \
    GL16(ARR[4], BA, "1024");  GL16(ARR[5], BB, "1024");  \
    GL16(ARR[6], BA, "3072");  GL16(ARR[7], BB, "3072"); } while (0)

// one tile-phase: wait K -> QK^T -> refill K(+2) -> softmax -> wait V -> PV -> refill V(+2)
#define TRIP_HALF(KARR, VARR, KT) do { \
    asm volatile("s_waitcnt vmcnt(24)" ::: "memory"); \
    __builtin_amdgcn_sched_barrier(0); \
    const bool act_ = (KT) < nt; \
    f32x4 sc[2][4]; \
    if (act_) { \
        __builtin_amdgcn_s_setprio(1); \
        _Pragma("unroll") \
        for (int st = 0; st < 4; ++st) { \
            bf16x8 k0 = __builtin_bit_cast(bf16x8, KARR[2 * st]); \
            bf16x8 k1 = __builtin_bit_cast(bf16x8, KARR[2 * st + 1]); \
            _Pragma("unroll") \
            for (int qs = 0; qs < 2; ++qs) { \
                f32x4 z = {0.f, 0.f, 0.f, 0.f}; \
                f32x4 cc = __builtin_amdgcn_mfma_f32_16x16x32_bf16(k0, qf[qs][0], z, 0, 0, 0); \
                sc[qs][st] = __builtin_amdgcn_mfma_f32_16x16x32_bf16(k1, qf[qs][1], cc, 0, 0, 0); \
            } \
        } \
        __builtin_amdgcn_s_setprio(0); \
    } \
    { int ti = (KT) + 2; if (ti > nm1) ti = nm1; \
      const char* ba_ = tb + (size_t)ti * TILE_BYTES + o_a; \
      const char* bb_ = tb + (size_t)ti * TILE_BYTES + o_b; \
      ISSUE8(KARR, ba_, bb_); } \
    u32x4 pw[2][2]; \
    if (act_) { \
        const int kv0 = (KT) * 64; \
        const bool maskit = ((KT) == nm1); \
        _Pragma("unroll") \
        for (int qs = 0; qs < 2; ++qs) { \
            _Pragma("unroll") \
            for (int st = 0; st < 4; ++st) { \
                f32x4 cc = sc[qs][st]; \
                if (maskit) { \
                    _Pragma("unroll") \
                    for (int r = 0; r < 4; ++r) { \
                        const int kv = kv0 + 32 * (st >> 1) + 8 * g + 4 * (st & 1) + r; \
                        if (kv > qrow[qs]) cc[r] = -INFINITY; \
                    } \
                } \
                f32x4 ev; \
                _Pragma("unroll") \
                for (int r = 0; r < 4; ++r) \
                    asm("v_exp_f32 %0, %1" : "=v"(ev[r]) : "v"(cc[r])); \
                ls[qs] += (ev[0] + ev[1]) + (ev[2] + ev[3]); \
                asm("v_cvt_pk_bf16_f32 %0, %1, %2" : "=v"(pw[qs][st >> 1][2 * (st & 1)])     : "v"(ev[0]), "v"(ev[1])); \
                asm("v_cvt_pk_bf16_f32 %0, %1, %2" : "=v"(pw[qs][st >> 1][2 * (st & 1) + 1]) : "v"(ev[2]), "v"(ev[3])); \
            } \
        } \
    } \
    asm volatile("s_waitcnt vmcnt(24)" ::: "memory"); \
    __builtin_amdgcn_sched_barrier(0); \
    if (act_) { \
        __builtin_amdgcn_s_setprio(1); \
        _Pragma("unroll") \
        for (int dt = 0; dt < 4; ++dt) { \
            bf16x8 v0 = __builtin_bit_cast(bf16x8, VARR[2 * dt]); \
            bf16x8 v1 = __builtin_bit_cast(bf16x8, VARR[2 * dt + 1]); \
            _Pragma("unroll") \
            for (int qs = 0; qs < 2; ++qs) { \
                acc[qs][dt] = __builtin_amdgcn_mfma_f32_16x16x32_bf16(v0, __builtin_bit_cast(bf16x8, pw[qs][0]), acc[qs][dt], 0, 0, 0); \
                acc[qs][dt] = __builtin_amdgcn_mfma_f32_16x16x32_bf16(v1, __builtin_bit_cast(bf16x8, pw[qs][1]), acc[qs][dt], 0, 0, 0); \
            } \
        } \
        __builtin_amdgcn_s_setprio(0); \
    } \
    { int ti = (KT) + 2; if (ti > nm1) ti = nm1; \
      const char* ba_ = tb + (size_t)ti * TILE_BYTES + 8192 + o_a; \
      const char* bb_ = tb + (size_t)ti * TILE_BYTES + 8192 + o_b; \
      ISSUE8(VARR, ba_, bb_); } \
} while (0)

// full causal kv-range [0, nt) for 32-row q-tile qt; depth-2 pipeline; writes O directly
__device__ __forceinline__ void do_tile16(
    const float* __restrict__ Q, const char* __restrict__ tb,
    int b0, int h, int qt, int nt, int lq, int g, float* __restrict__ O)
{
    const int nm1 = nt - 1;
    int qrow[2];
    qrow[0] = qt * 32 + lq;
    qrow[1] = qt * 32 + 16 + lq;

    // Q fragments (B-operand), scale*log2e folded => scores in exp2 domain
    bf16x8 qf[2][2];
    #pragma unroll
    for (int qs = 0; qs < 2; ++qs) {
        const float* qptr = Q + (((size_t)(b0 * L_ + qrow[qs])) * H_ + h) * E_;
        #pragma unroll
        for (int eb = 0; eb < 2; ++eb) {
            const float* pq = qptr + eb * 32 + g * 8;
            f32x4 a = *(const f32x4*)pq;
            f32x4 b = *(const f32x4*)(pq + 4);
            bf16x8 qv;
            #pragma unroll
            for (int k = 0; k < 4; ++k) {
                qv[k]     = (short)f2bf(a[k] * SCL);
                qv[4 + k] = (short)f2bf(b[k] * SCL);
            }
            qf[qs][eb] = qv;
        }
    }

    const int mm  = (lq & 7) << 4;
    const int o_a = lq * 128 + ((16 * g) ^ mm) + 3072;
    const int o_b = lq * 128 + ((64 + 16 * g) ^ mm) + 3072;

    u32x4 kA[8], kB[8], vA[8], vB[8];   // depth-2: 2 K tiles + 2 V tiles in registers
    f32x4 acc[2][4] = {};
    float ls[2] = {0.f, 0.f};

    // prologue: K0,V0,K1,V1 (issue order == retirement order for vmcnt counting)
    {
        const char* a0 = tb + o_a;
        const char* b0_ = tb + o_b;
        ISSUE8(kA, a0, b0_);
        ISSUE8(vA, a0 + 8192, b0_ + 8192);
        int t1 = (1 > nm1) ? nm1 : 1;
        const char* a1 = tb + (size_t)t1 * TILE_BYTES + o_a;
        const char* b1 = tb + (size_t)t1 * TILE_BYTES + o_b;
        ISSUE8(kB, a1, b1);
        ISSUE8(vB, a1 + 8192, b1 + 8192);
    }

    for (int kt = 0; kt < nt; kt += 2) {
        TRIP_HALF(kA, vA, kt);
        TRIP_HALF(kB, vB, kt + 1);
    }
    asm volatile("s_waitcnt vmcnt(0)" ::: "memory");   // drain stale prefetches before regs reused
    __builtin_amdgcn_sched_barrier(0);

    // epilogue: reduce l across the 4 lane-groups, divide, store
    #pragma unroll
    for (int qs = 0; qs < 2; ++qs) {
        float l = ls[qs] + __shfl_xor(ls[qs], 16);
        l += __shfl_xor(l, 32);
        const float inv = 1.0f / l;
        float* op = O + (((size_t)(b0 * L_ + qrow[qs])) * H_ + h) * D_;
        #pragma unroll
        for (int dt = 0; dt < 4; ++dt) {
            f32x4 o;
            #pragma unroll
            for (int r = 0; r < 4; ++r) o[r] = acc[qs][dt][r] * inv;
            *(f32x4*)(op + dt * 16 + 4 * g) = o;
        }
    }
}

__global__ __launch_bounds__(256, 1) void attn16(const float* __restrict__ Q,
                                                 const unsigned short* __restrict__ ws,
                                                 float* __restrict__ O)
{
    const int tid  = threadIdx.x;
    const int lane = tid & 63;
    const int w    = tid >> 6;        // wave 0..3, fully independent (no LDS, no barriers)
    const int lq   = lane & 15;
    const int g    = lane >> 4;

    const int bid = blockIdx.x;
    const int bh  = bid & 31;         // XCD bh%8 == prep's XCD for this image
    const int j   = bid >> 5;         // 0..7
    const int b0  = bh >> 3, h = bh & 7;

    // wave-job: complementary pair {p, 63-p} -> exactly 33 kv-tile iterations per wave
    const int p   = j * 4 + w;                  // 0..31
    const int ntA = (p >> 1) + 1;
    const int ntB = ((63 - p) >> 1) + 1;        // ntA + ntB == 33

    const char* tb = (const char*)ws + (size_t)bh * NT_ * TILE_BYTES;

    do_tile16(Q, tb, b0, h, p,      ntA, lq, g, O);
    do_tile16(Q, tb, b0, h, 63 - p, ntB, lq, g, O);
}

// ---------------- fallback (round-1 kernel, proven) for tiny ws ----------------
#define KPITCH 72
__global__ __launch_bounds__(256, 2) void attn_fwd_fb(
    const float* __restrict__ Q, const float* __restrict__ K,
    const float* __restrict__ V, float* __restrict__ O)
{
    __shared__ unsigned short Klds[64 * KPITCH];
    __shared__ unsigned short Vlds[64 * KPITCH];
    const int tid = threadIdx.x, lane = tid & 63, w = tid >> 6;
    const int lq = lane & 15, g = lane >> 4;
    const int bid = blockIdx.x, qb = bid & 31, bh = bid >> 5;
    const int b0 = bh >> 3, h = bh & 7;
    const int q0 = qb * 64, qrow = q0 + w * 16 + lq;
    const float* qptr = Q + ((size_t)(b0 * L_ + qrow) * H_ + h) * E_;
    bf16x8 qf[2];
    #pragma unroll
    for (int eb = 0; eb < 2; ++eb) {
        const float* pp = qptr + eb * 32 + g * 8;
        f32x4 a = *(const f32x4*)pp; f32x4 b = *(const f32x4*)(pp + 4);
        bf16x8 qv;
        #pragma unroll
        for (int jq = 0; jq < 4; ++jq) { qv[jq] = (short)f2bf(a[jq] * 0.125f); qv[4 + jq] = (short)f2bf(b[jq] * 0.125f); }
        qf[eb] = qv;
    }
    const int tr = tid >> 2, tc = tid & 3;
    const int rh = rho(tr);
    f32x4 acc[4] = {};
    float mrow = -INFINITY, lrow = 0.f;
    for (int kt = 0; kt < qb + 1; ++kt) {
        const int kv0 = kt * 64;
        __syncthreads();
        {
            const float* krow = K + ((size_t)((b0 * S_ + kv0 + tr)) * H_ + h) * E_;
            const float* vrow = V + ((size_t)((b0 * S_ + kv0 + tr)) * H_ + h) * D_;
            #pragma unroll
            for (int i = 0; i < 4; ++i) {
                const int e0 = tc * 4 + i * 16;
                f32x4 k4 = *(const f32x4*)(krow + e0);
                unsigned int lo = (unsigned)f2bf(k4[0]) | ((unsigned)f2bf(k4[1]) << 16);
                unsigned int hi = (unsigned)f2bf(k4[2]) | ((unsigned)f2bf(k4[3]) << 16);
                *(uint2*)&Klds[rh * KPITCH + e0] = make_uint2(lo, hi);
                f32x4 v4 = *(const f32x4*)(vrow + e0);
                #pragma unroll
                for (int k2 = 0; k2 < 4; ++k2) Vlds[(e0 + k2) * KPITCH + tr] = f2bf(v4[k2]);
            }
        }
        __syncthreads();
        f32x4 sc[4];
        #pragma unroll
        for (int st = 0; st < 4; ++st) {
            const unsigned short* kr = &Klds[(st * 16 + lq) * KPITCH];
            bf16x8 ka0 = *(const bf16x8*)(kr + 8 * g);
            bf16x8 ka1 = *(const bf16x8*)(kr + 32 + 8 * g);
            f32x4 cc = {0.f, 0.f, 0.f, 0.f};
            cc = __builtin_amdgcn_mfma_f32_16x16x32_bf16(ka0, qf[0], cc, 0, 0, 0);
            cc = __builtin_amdgcn_mfma_f32_16x16x32_bf16(ka1, qf[1], cc, 0, 0, 0);
            sc[st] = cc;
        }
        float tmax = -INFINITY;
        #pragma unroll
        for (int st = 0; st < 4; ++st) {
            const int kvb = kv0 + 32 * (st >> 1) + 8 * g + 4 * (st & 1);
            #pragma unroll
            for (int r = 0; r < 4; ++r) { if (kvb + r > qrow) sc[st][r] = -INFINITY; tmax = fmaxf(tmax, sc[st][r]); }
        }
        tmax = fmaxf(tmax, __shfl_xor(tmax, 16));
        tmax = fmaxf(tmax, __shfl_xor(tmax, 32));
        const float mnew = fmaxf(mrow, tmax);
        const float corr = __expf(mrow - mnew);
        float pv[4][4]; float tsum = 0.f;
        #pragma unroll
        for (int st = 0; st < 4; ++st)
            #pragma unroll
            for (int r = 0; r < 4; ++r) { float e = __expf(sc[st][r] - mnew); pv[st][r] = e; tsum += e; }
        tsum += __shfl_xor(tsum, 16); tsum += __shfl_xor(tsum, 32);
        lrow = lrow * corr + tsum; mrow = mnew;
        #pragma unroll
        for (int dt = 0; dt < 4; ++dt)
            #pragma unroll
            for (int r = 0; r < 4; ++r) acc[dt][r] *= corr;
        bf16x8 pb[2];
        #pragma unroll
        for (int bb = 0; bb < 2; ++bb)
            #pragma unroll
            for (int s = 0; s < 2; ++s)
                #pragma unroll
                for (int r = 0; r < 4; ++r) pb[bb][4 * s + r] = (short)f2bf(pv[2 * bb + s][r]);
        #pragma unroll
        for (int bb = 0; bb < 2; ++bb)
            #pragma unroll
            for (int dt = 0; dt < 4; ++dt) {
                bf16x8 va = *(const bf16x8*)&Vlds[(dt * 16 + lq) * KPITCH + 32 * bb + 8 * g];
                acc[dt] = __builtin_amdgcn_mfma_f32_16x16x32_bf16(va, pb[bb], acc[dt], 0, 0, 0);
            }
    }
    const float inv = 1.0f / lrow;
    float* optr = O + ((size_t)(b0 * L_ + qrow) * H_ + h) * D_;
    #pragma unroll
    for (int dt = 0; dt < 4; ++dt) {
        f32x4 o;
        #pragma unroll
        for (int r = 0; r < 4; ++r) o[r] = acc[dt][r] * inv;
        *(f32x4*)(optr + dt * 16 + 4 * g) = o;
    }
}

extern "C" void kernel_launch(void* const* d_in, const int* in_sizes, int n_in,
                              void* d_out, int out_size, void* d_ws, size_t ws_size,
                              hipStream_t stream) {
    const float* Q = (const float*)d_in[0];
    const float* K = (const float*)d_in[1];
    const float* V = (const float*)d_in[2];
    float* O = (float*)d_out;
    if (ws_size >= WS_NEEDED) {
        prep_kv<<<dim3(B_ * H_ * NT_), 256, 0, stream>>>(K, V, (unsigned short*)d_ws);
        attn16<<<dim3(256), 256, 0, stream>>>(Q, (const unsigned short*)d_ws, O);
    } else {
        attn_fwd_fb<<<dim3(B_ * H_ * 32), 256, 0, stream>>>(Q, K, V, O);
    }
}

// Round 16
// 46.947 us; speedup vs baseline: 1.1300x; 1.1161x over previous
//
#include <hip/hip_runtime.h>
#include <math.h>

typedef __attribute__((ext_vector_type(8))) short bf16x8;
typedef __attribute__((ext_vector_type(4))) float f32x4;
typedef __attribute__((ext_vector_type(4))) unsigned int u32x4;

#define B_ 4
#define L_ 2048
#define S_ 2048
#define H_ 8
#define E_ 64
#define D_ 64
#define NT_ 32
#define TILE_BYTES 16384
#define WS_NEEDED ((size_t)B_ * H_ * NT_ * TILE_BYTES)   // 16 MB tile images
#define SCL (0.125f * 1.44269504088896f)                  // 1/sqrt(E) * log2(e)

__device__ __forceinline__ unsigned short f2bf(float x) {
    unsigned int u = __builtin_bit_cast(unsigned int, x);
    u += 0x7fffu + ((u >> 16) & 1u);
    return (unsigned short)(u >> 16);
}
// kv-row permute so S^T C-fragment layout == PV A-operand layout (verified rounds 1-15)
__device__ __forceinline__ int rho(int r) {
    return (r & 32) | (((r >> 2) & 1) << 4) | (((r >> 3) & 3) << 2) | (r & 3);
}
__device__ __forceinline__ void gload16(const void* g, void* l) {
    __builtin_amdgcn_global_load_lds((const __attribute__((address_space(1))) unsigned int*)g,
                                     (__attribute__((address_space(3))) unsigned int*)l, 16, 0, 0);
}

// ---------------- prep: K -> bf16 tile image, V -> V^T image; XCD-aligned to consumer ----------------
__global__ __launch_bounds__(256) void prep_kv(const float* __restrict__ K,
                                               const float* __restrict__ V,
                                               unsigned short* __restrict__ ws)
{
    __shared__ __align__(16) unsigned short vt[64][80];
    const int tid = threadIdx.x;
    const int bid = blockIdx.x;
    const int kt  = bid >> 5;
    const int bh  = (((bid >> 3) & 3) << 3) | (bid & 7);      // bid%8 == bh%8
    const int b   = bh >> 3, h = bh & 7;
    const int s0  = kt * 64;
    const int r   = tid >> 2;
    const int e0  = (tid & 3) * 16;

    const float* krow = K + (((size_t)(b * S_ + s0 + r)) * H_ + h) * E_ + e0;
    const float* vrow = V + (((size_t)(b * S_ + s0 + r)) * H_ + h) * D_ + e0;
    char* tile = (char*)(ws) + ((size_t)(bh * NT_ + kt) * TILE_BYTES);

    unsigned short kb[16];
    #pragma unroll
    for (int i = 0; i < 4; ++i) {
        f32x4 k4 = *(const f32x4*)(krow + i * 4);
        #pragma unroll
        for (int jq = 0; jq < 4; ++jq) kb[i * 4 + jq] = f2bf(k4[jq]);
    }
    {
        const int rr = rho(r);
        const int m  = (rr & 7) << 4;
        char* kbase = tile + rr * 128;
        u32x4 lo, hi;
        #pragma unroll
        for (int jq = 0; jq < 4; ++jq) {
            lo[jq] = (unsigned)kb[2 * jq] | ((unsigned)kb[2 * jq + 1] << 16);
            hi[jq] = (unsigned)kb[8 + 2 * jq] | ((unsigned)kb[9 + 2 * jq] << 16);
        }
        *(u32x4*)(kbase + ((2 * e0) ^ m))      = lo;
        *(u32x4*)(kbase + ((2 * e0 + 16) ^ m)) = hi;
    }
    #pragma unroll
    for (int i = 0; i < 4; ++i) {
        f32x4 v4 = *(const f32x4*)(vrow + i * 4);
        #pragma unroll
        for (int jq = 0; jq < 4; ++jq) vt[e0 + i * 4 + jq][r] = f2bf(v4[jq]);
    }
    __syncthreads();
    {
        const int d  = tid >> 2;
        const int c0 = (tid & 3) * 16;
        const int m  = (d & 7) << 4;
        char* vbase = tile + 8192 + d * 128;
        u32x4 lo = *(const u32x4*)&vt[d][c0];
        u32x4 hi = *(const u32x4*)&vt[d][c0 + 8];
        *(u32x4*)(vbase + ((2 * c0) ^ m))      = lo;
        *(u32x4*)(vbase + ((2 * c0 + 16) ^ m)) = hi;
    }
}

// ---- attn17: 4-wave/128-row blocks, 4-buf LDS ring, ONE barrier/iter, depth-2 counted vmcnt ----
__global__ __launch_bounds__(256, 2) void attn17(const float* __restrict__ Q,
                                                 const unsigned short* __restrict__ ws,
                                                 float* __restrict__ O)
{
    __shared__ __align__(16) char pool[4 * 16384];   // 64 KB ring

    const int tid  = threadIdx.x;
    const int lane = tid & 63;
    const int w    = tid >> 6;        // wave 0..3
    const int lq   = lane & 15;
    const int gl   = lane >> 4;

    const int bid = blockIdx.x;
    const int bh  = bid & 31;                     // XCD bh%8 == prep's XCD
    const int q   = bid >> 5;                     // 0..15
    const int jj  = (q < 8) ? (15 - q) : (q - 8); // desc then asc: co-resident pair sums to 34 iters
    const int b0  = bh >> 3, h = bh & 7;

    const int nt = 2 * jj + 2;                    // kv tiles for this block's 128 rows
    const int c  = 2 * jj + (w >> 1);             // this wave's diagonal tile
    const int q0 = jj * 128 + w * 32;
    int qrow[2];
    qrow[0] = q0 + lq;
    qrow[1] = q0 + 16 + lq;

    // Q fragments (B-operand), scale*log2e folded => scores in exp2 domain
    bf16x8 qf[2][2];
    #pragma unroll
    for (int qs = 0; qs < 2; ++qs) {
        const float* qptr = Q + (((size_t)(b0 * L_ + qrow[qs])) * H_ + h) * E_;
        #pragma unroll
        for (int eb = 0; eb < 2; ++eb) {
            const float* pq = qptr + eb * 32 + gl * 8;
            f32x4 a = *(const f32x4*)pq;
            f32x4 b = *(const f32x4*)(pq + 4);
            bf16x8 qv;
            #pragma unroll
            for (int k = 0; k < 4; ++k) {
                qv[k]     = (short)f2bf(a[k] * SCL);
                qv[4 + k] = (short)f2bf(b[k] * SCL);
            }
            qf[qs][eb] = qv;
        }
    }

    f32x4 acc[2][4] = {};
    float ls[2] = {0.f, 0.f};

    const char* tb = (const char*)ws + (size_t)bh * NT_ * TILE_BYTES;

    // each thread stages 4x16B of a 16KB tile
    #define STAGE17(T, BUF) do { \
        const char* gp_ = tb + (size_t)(T) * TILE_BYTES + tid * 16; \
        char* lp_ = pool + (BUF) * 16384 + tid * 16; \
        gload16(gp_, lp_);                 gload16(gp_ + 4096, lp_ + 4096); \
        gload16(gp_ + 8192, lp_ + 8192);   gload16(gp_ + 12288, lp_ + 12288); \
    } while (0)

    STAGE17(0, 0);
    STAGE17(1, 1);                                // nt >= 2 always
    for (int i = 0; i < nt; ++i) {
        if (i + 2 < nt) STAGE17(i + 2, (i + 2) & 3);   // buf freed at barrier of iter i-1
        const int rem = nt - 1 - i;
        if (rem >= 2)      asm volatile("s_waitcnt vmcnt(8)" ::: "memory");
        else if (rem == 1) asm volatile("s_waitcnt vmcnt(4)" ::: "memory");
        else               asm volatile("s_waitcnt vmcnt(0)" ::: "memory");
        __builtin_amdgcn_s_barrier();             // all waves' tile-i loads landed; computes i-1 done
        __builtin_amdgcn_sched_barrier(0);

        if (i <= c) {
            const char* Kl = pool + (i & 3) * 16384;
            const char* Vl = Kl + 8192;
            const int kv0 = i * 64;
            const bool maskit = (i == c);

            u32x4 pw[2][2];
            #pragma unroll
            for (int st = 0; st < 4; ++st) {
                const int row = st * 16 + lq;
                const int mm = (row & 7) << 4;
                const char* kr = Kl + row * 128;
                bf16x8 k0 = *(const bf16x8*)(kr + ((16 * gl) ^ mm));
                bf16x8 k1 = *(const bf16x8*)(kr + ((64 + 16 * gl) ^ mm));
                #pragma unroll
                for (int qs = 0; qs < 2; ++qs) {
                    f32x4 z = {0.f, 0.f, 0.f, 0.f};
                    __builtin_amdgcn_s_setprio(1);
                    f32x4 cc = __builtin_amdgcn_mfma_f32_16x16x32_bf16(k0, qf[qs][0], z, 0, 0, 0);
                    cc = __builtin_amdgcn_mfma_f32_16x16x32_bf16(k1, qf[qs][1], cc, 0, 0, 0);
                    __builtin_amdgcn_s_setprio(0);
                    if (maskit) {
                        #pragma unroll
                        for (int r = 0; r < 4; ++r) {
                            const int kv = kv0 + 32 * (st >> 1) + 8 * gl + 4 * (st & 1) + r;
                            if (kv > qrow[qs]) cc[r] = -INFINITY;
                        }
                    }
                    f32x4 ev;
                    #pragma unroll
                    for (int r = 0; r < 4; ++r)
                        asm("v_exp_f32 %0, %1" : "=v"(ev[r]) : "v"(cc[r]));
                    ls[qs] += (ev[0] + ev[1]) + (ev[2] + ev[3]);
                    asm("v_cvt_pk_bf16_f32 %0, %1, %2" : "=v"(pw[qs][st >> 1][2 * (st & 1)])     : "v"(ev[0]), "v"(ev[1]));
                    asm("v_cvt_pk_bf16_f32 %0, %1, %2" : "=v"(pw[qs][st >> 1][2 * (st & 1) + 1]) : "v"(ev[2]), "v"(ev[3]));
                }
            }

            #pragma unroll
            for (int dt = 0; dt < 4; ++dt) {
                const int row = dt * 16 + lq;
                const int mm = (row & 7) << 4;
                bf16x8 v0 = *(const bf16x8*)(Vl + row * 128 + ((16 * gl) ^ mm));
                bf16x8 v1 = *(const bf16x8*)(Vl + row * 128 + ((64 + 16 * gl) ^ mm));
                __builtin_amdgcn_s_setprio(1);
                #pragma unroll
                for (int qs = 0; qs < 2; ++qs) {
                    acc[qs][dt] = __builtin_amdgcn_mfma_f32_16x16x32_bf16(v0, __builtin_bit_cast(bf16x8, pw[qs][0]), acc[qs][dt], 0, 0, 0);
                    acc[qs][dt] = __builtin_amdgcn_mfma_f32_16x16x32_bf16(v1, __builtin_bit_cast(bf16x8, pw[qs][1]), acc[qs][dt], 0, 0, 0);
                }
                __builtin_amdgcn_s_setprio(0);
            }
        }
    }
    #undef STAGE17

    // epilogue: reduce l across lane-groups, normalize, store directly (no split-K)
    #pragma unroll
    for (int qs = 0; qs < 2; ++qs) {
        float l = ls[qs] + __shfl_xor(ls[qs], 16);
        l += __shfl_xor(l, 32);
        const float inv = 1.0f / l;
        float* op = O + (((size_t)(b0 * L_ + qrow[qs])) * H_ + h) * D_;
        #pragma unroll
        for (int dt = 0; dt < 4; ++dt) {
            f32x4 o;
            #pragma unroll
            for (int r = 0; r < 4; ++r) o[r] = acc[qs][dt][r] * inv;
            *(f32x4*)(op + dt * 16 + 4 * gl) = o;
        }
    }
}

// ---------------- fallback (round-1 kernel, proven) for tiny ws ----------------
#define KPITCH 72
__global__ __launch_bounds__(256, 2) void attn_fwd_fb(
    const float* __restrict__ Q, const float* __restrict__ K,
    const float* __restrict__ V, float* __restrict__ O)
{
    __shared__ unsigned short Klds[64 * KPITCH];
    __shared__ unsigned short Vlds[64 * KPITCH];
    const int tid = threadIdx.x, lane = tid & 63, w = tid >> 6;
    const int lq = lane & 15, g = lane >> 4;
    const int bid = blockIdx.x, qb = bid & 31, bh = bid >> 5;
    const int b0 = bh >> 3, h = bh & 7;
    const int q0 = qb * 64, qrow = q0 + w * 16 + lq;
    const float* qptr = Q + ((size_t)(b0 * L_ + qrow) * H_ + h) * E_;
    bf16x8 qf[2];
    #pragma unroll
    for (int eb = 0; eb < 2; ++eb) {
        const float* pp = qptr + eb * 32 + g * 8;
        f32x4 a = *(const f32x4*)pp; f32x4 b = *(const f32x4*)(pp + 4);
        bf16x8 qv;
        #pragma unroll
        for (int jq = 0; jq < 4; ++jq) { qv[jq] = (short)f2bf(a[jq] * 0.125f); qv[4 + jq] = (short)f2bf(b[jq] * 0.125f); }
        qf[eb] = qv;
    }
    const int tr = tid >> 2, tc = tid & 3;
    const int rh = rho(tr);
    f32x4 acc[4] = {};
    float mrow = -INFINITY, lrow = 0.f;
    for (int kt = 0; kt < qb + 1; ++kt) {
        const int kv0 = kt * 64;
        __syncthreads();
        {
            const float* krow = K + ((size_t)((b0 * S_ + kv0 + tr)) * H_ + h) * E_;
            const float* vrow = V + ((size_t)((b0 * S_ + kv0 + tr)) * H_ + h) * D_;
            #pragma unroll
            for (int i = 0; i < 4; ++i) {
                const int e0 = tc * 4 + i * 16;
                f32x4 k4 = *(const f32x4*)(krow + e0);
                unsigned int lo = (unsigned)f2bf(k4[0]) | ((unsigned)f2bf(k4[1]) << 16);
                unsigned int hi = (unsigned)f2bf(k4[2]) | ((unsigned)f2bf(k4[3]) << 16);
                *(uint2*)&Klds[rh * KPITCH + e0] = make_uint2(lo, hi);
                f32x4 v4 = *(const f32x4*)(vrow + e0);
                #pragma unroll
                for (int k2 = 0; k2 < 4; ++k2) Vlds[(e0 + k2) * KPITCH + tr] = f2bf(v4[k2]);
            }
        }
        __syncthreads();
        f32x4 sc[4];
        #pragma unroll
        for (int st = 0; st < 4; ++st) {
            const unsigned short* kr = &Klds[(st * 16 + lq) * KPITCH];
            bf16x8 ka0 = *(const bf16x8*)(kr + 8 * g);
            bf16x8 ka1 = *(const bf16x8*)(kr + 32 + 8 * g);
            f32x4 cc = {0.f, 0.f, 0.f, 0.f};
            cc = __builtin_amdgcn_mfma_f32_16x16x32_bf16(ka0, qf[0], cc, 0, 0, 0);
            cc = __builtin_amdgcn_mfma_f32_16x16x32_bf16(ka1, qf[1], cc, 0, 0, 0);
            sc[st] = cc;
        }
        float tmax = -INFINITY;
        #pragma unroll
        for (int st = 0; st < 4; ++st) {
            const int kvb = kv0 + 32 * (st >> 1) + 8 * g + 4 * (st & 1);
            #pragma unroll
            for (int r = 0; r < 4; ++r) { if (kvb + r > qrow) sc[st][r] = -INFINITY; tmax = fmaxf(tmax, sc[st][r]); }
        }
        tmax = fmaxf(tmax, __shfl_xor(tmax, 16));
        tmax = fmaxf(tmax, __shfl_xor(tmax, 32));
        const float mnew = fmaxf(mrow, tmax);
        const float corr = __expf(mrow - mnew);
        float pv[4][4]; float tsum = 0.f;
        #pragma unroll
        for (int st = 0; st < 4; ++st)
            #pragma unroll
            for (int r = 0; r < 4; ++r) { float e = __expf(sc[st][r] - mnew); pv[st][r] = e; tsum += e; }
        tsum += __shfl_xor(tsum, 16); tsum += __shfl_xor(tsum, 32);
        lrow = lrow * corr + tsum; mrow = mnew;
        #pragma unroll
        for (int dt = 0; dt < 4; ++dt)
            #pragma unroll
            for (int r = 0; r < 4; ++r) acc[dt][r] *= corr;
        bf16x8 pb[2];
        #pragma unroll
        for (int bb = 0; bb < 2; ++bb)
            #pragma unroll
            for (int s = 0; s < 2; ++s)
                #pragma unroll
                for (int r = 0; r < 4; ++r) pb[bb][4 * s + r] = (short)f2bf(pv[2 * bb + s][r]);
        #pragma unroll
        for (int bb = 0; bb < 2; ++bb)
            #pragma unroll
            for (int dt = 0; dt < 4; ++dt) {
                bf16x8 va = *(const bf16x8*)&Vlds[(dt * 16 + lq) * KPITCH + 32 * bb + 8 * g];
                acc[dt] = __builtin_amdgcn_mfma_f32_16x16x32_bf16(va, pb[bb], acc[dt], 0, 0, 0);
            }
    }
    const float inv = 1.0f / lrow;
    float* optr = O + ((size_t)(b0 * L_ + qrow) * H_ + h) * D_;
    #pragma unroll
    for (int dt = 0; dt < 4; ++dt) {
        f32x4 o;
        #pragma unroll
        for (int r = 0; r < 4; ++r) o[r] = acc[dt][r] * inv;
        *(f32x4*)(optr + dt * 16 + 4 * g) = o;
    }
}

extern "C" void kernel_launch(void* const* d_in, const int* in_sizes, int n_in,
                              void* d_out, int out_size, void* d_ws, size_t ws_size,
                              hipStream_t stream) {
    const float* Q = (const float*)d_in[0];
    const float* K = (const float*)d_in[1];
    const float* V = (const float*)d_in[2];
    float* O = (float*)d_out;
    if (ws_size >= WS_NEEDED) {
        prep_kv<<<dim3(B_ * H_ * NT_), 256, 0, stream>>>(K, V, (unsigned short*)d_ws);
        attn17<<<dim3(512), 256, 0, stream>>>(Q, (const unsigned short*)d_ws, O);
    } else {
        attn_fwd_fb<<<dim3(B_ * H_ * 32), 256, 0, stream>>>(Q, K, V, O);
    }
}